// Round 1
// baseline (190.432 us; speedup 1.0000x reference)
//
#include <hip/hip_runtime.h>
#include <hip/hip_bf16.h>

// QLSTM: T=512, B=256, D_IN=128, D_H=128.
// Key simplification: gates are per-batch SCALARS broadcast over hidden dim,
// so h and c are uniform across hidden dim. comb@W[0] = x@W[0][:128] + h*sum(W[0][128:]).
// Pipeline: (1) xz GEMV (mem-bound), (2) 512-step scalar scan (256 threads),
// (3) broadcast h[t,b] to 128 cols + hx/cx tails (mem-bound).

constexpr int T = 512;
constexpr int Bsz = 256;
constexpr int D_IN = 128;
constexpr int R = T * Bsz;          // 131072 rows

// ---------------- Kernel 1: xz[g][t*B+b] = x[t,b,:]·Wg[0][:128] + bg[0] + thg[0]
// One wave (64 lanes) per (t,b) row. Lanes read x[row,lane] and x[row,lane+64].
__global__ __launch_bounds__(256) void xz_kernel(
    const float* __restrict__ x,
    const float* __restrict__ Wf, const float* __restrict__ bf, const float* __restrict__ tf,
    const float* __restrict__ Wi, const float* __restrict__ bi, const float* __restrict__ ti,
    const float* __restrict__ Wu, const float* __restrict__ bu, const float* __restrict__ tu,
    const float* __restrict__ Wo, const float* __restrict__ bo, const float* __restrict__ to_,
    float* __restrict__ xz)
{
    const int wave = blockIdx.x * 4 + (threadIdx.x >> 6);
    const int lane = threadIdx.x & 63;
    const float* xr = x + (size_t)wave * D_IN;
    const float x0 = xr[lane];
    const float x1 = xr[lane + 64];

    float pf = x0 * Wf[lane] + x1 * Wf[lane + 64];
    float pi = x0 * Wi[lane] + x1 * Wi[lane + 64];
    float pu = x0 * Wu[lane] + x1 * Wu[lane + 64];
    float po = x0 * Wo[lane] + x1 * Wo[lane + 64];

#pragma unroll
    for (int off = 32; off; off >>= 1) {
        pf += __shfl_xor(pf, off, 64);
        pi += __shfl_xor(pi, off, 64);
        pu += __shfl_xor(pu, off, 64);
        po += __shfl_xor(po, off, 64);
    }
    if (lane == 0) {
        xz[0 * R + wave] = pf + bf[0] + tf[0];
        xz[1 * R + wave] = pi + bi[0] + ti[0];
        xz[2 * R + wave] = pu + bu[0] + tu[0];
        xz[3 * R + wave] = po + bo[0] + to_[0];
    }
}

// ---------------- Kernel 2: sequential scan, one thread per batch element.
__device__ __forceinline__ float fsig(float x) {
    return __builtin_amdgcn_rcpf(1.0f + __expf(-x));
}
__device__ __forceinline__ float ftanh(float x) {
    float e = __expf(-2.0f * x);
    return (1.0f - e) * __builtin_amdgcn_rcpf(1.0f + e);
}

__global__ __launch_bounds__(256) void scan_kernel(
    const float* __restrict__ xz,
    const float* __restrict__ Wf, const float* __restrict__ Wi,
    const float* __restrict__ Wu, const float* __restrict__ Wo,
    float* __restrict__ hscan, float* __restrict__ cfin)
{
    const int b = threadIdx.x;
    __shared__ float swh[4];
    if (b < 4) {
        const float* W = (b == 0) ? Wf : (b == 1) ? Wi : (b == 2) ? Wu : Wo;
        float s = 0.0f;
        for (int k = 0; k < 128; ++k) s += W[128 + k];
        swh[b] = s;
    }
    __syncthreads();
    const float swf = swh[0], swi = swh[1], swu = swh[2], swo = swh[3];

    float h = 0.0f, c = 0.0f;
    // software prefetch of next step's xz
    float nzf = xz[0 * R + b], nzi = xz[1 * R + b], nzu = xz[2 * R + b], nzo = xz[3 * R + b];
    for (int t = 0; t < T; ++t) {
        const float zf0 = nzf, zi0 = nzi, zu0 = nzu, zo0 = nzo;
        if (t + 1 < T) {
            const int idx = (t + 1) * Bsz + b;
            nzf = xz[0 * R + idx];
            nzi = xz[1 * R + idx];
            nzu = xz[2 * R + idx];
            nzo = xz[3 * R + idx];
        }
        const float f = fsig(__cosf(zf0 + h * swf));
        const float i = fsig(__cosf(zi0 + h * swi));
        const float g = ftanh(__cosf(zu0 + h * swu));
        const float o = fsig(__cosf(zo0 + h * swo));
        c = f * c + i * g;
        h = o * ftanh(c);
        hscan[t * Bsz + b] = h;
    }
    cfin[b] = c;
}

// ---------------- Kernel 3: broadcast h[t,b] across 128 hidden cols, + hx/cx tails.
// One float4 per thread; 32 float4 per output row.
__global__ __launch_bounds__(256) void bcast_kernel(
    const float* __restrict__ hscan, const float* __restrict__ cfin,
    float4* __restrict__ out)
{
    const unsigned i = blockIdx.x * 256u + threadIdx.x;  // float4 index
    const unsigned row = i >> 5;                          // output row (128 floats)
    float v;
    if (row < (unsigned)R) {
        v = hscan[row];
    } else {
        const unsigned r2 = row - (unsigned)R;
        v = (r2 < (unsigned)Bsz) ? hscan[(T - 1) * Bsz + r2] : cfin[r2 - (unsigned)Bsz];
    }
    out[i] = make_float4(v, v, v, v);
}

extern "C" void kernel_launch(void* const* d_in, const int* in_sizes, int n_in,
                              void* d_out, int out_size, void* d_ws, size_t ws_size,
                              hipStream_t stream)
{
    const float* x  = (const float*)d_in[0];
    const float* Wf = (const float*)d_in[1];
    const float* bf = (const float*)d_in[2];
    const float* tf = (const float*)d_in[3];
    const float* Wi = (const float*)d_in[4];
    const float* bi = (const float*)d_in[5];
    const float* ti = (const float*)d_in[6];
    const float* Wu = (const float*)d_in[7];
    const float* bu = (const float*)d_in[8];
    const float* tu = (const float*)d_in[9];
    const float* Wo = (const float*)d_in[10];
    const float* bo = (const float*)d_in[11];
    const float* to_ = (const float*)d_in[12];

    float* ws    = (float*)d_ws;
    float* xz    = ws;            // 4*R floats
    float* hscan = ws + 4 * R;    // R floats
    float* cfin  = ws + 5 * R;    // Bsz floats

    xz_kernel<<<R / 4, 256, 0, stream>>>(x, Wf, bf, tf, Wi, bi, ti, Wu, bu, tu, Wo, bo, to_, xz);
    scan_kernel<<<1, 256, 0, stream>>>(xz, Wf, Wi, Wu, Wo, hscan, cfin);

    const int total_f4 = (R + 2 * Bsz) * 32;              // 4,210,688
    bcast_kernel<<<total_f4 / 256, 256, 0, stream>>>(hscan, cfin, (float4*)d_out);
}

// Round 2
// 126.425 us; speedup vs baseline: 1.5063x; 1.5063x over previous
//
#include <hip/hip_runtime.h>
#include <hip/hip_bf16.h>

// QLSTM: T=512, B=256, D_IN=128, D_H=128.
// Gates are per-batch SCALARS broadcast over hidden dim => h,c uniform across
// hidden dim. comb@W[0] = x@W[0][:128] + h*sum(W[0][128:]).
// Pipeline: (1) xz GEMV -> packed float4 per (t,b)  (mem-bound),
//           (2) 512-step scalar scan, 256 threads, depth-16 register prefetch,
//           (3) broadcast h[t,b] to 128 cols + hx/cx tails (mem-bound).

constexpr int T = 512;
constexpr int Bsz = 256;
constexpr int D_IN = 128;
constexpr int R = T * Bsz;          // 131072 rows

// ---------------- Kernel 1: xz[row] = float4(zf, zi, zu, zo), row = t*B+b
// One wave (64 lanes) per row. z = x[row,:]·Wg[0][:128] + bg[0] + thg[0].
__global__ __launch_bounds__(256) void xz_kernel(
    const float* __restrict__ x,
    const float* __restrict__ Wf, const float* __restrict__ bf, const float* __restrict__ tf,
    const float* __restrict__ Wi, const float* __restrict__ bi, const float* __restrict__ ti,
    const float* __restrict__ Wu, const float* __restrict__ bu, const float* __restrict__ tu,
    const float* __restrict__ Wo, const float* __restrict__ bo, const float* __restrict__ to_,
    float4* __restrict__ xz)
{
    const int wave = blockIdx.x * 4 + (threadIdx.x >> 6);
    const int lane = threadIdx.x & 63;
    const float* xr = x + (size_t)wave * D_IN;
    const float x0 = xr[lane];
    const float x1 = xr[lane + 64];

    float pf = x0 * Wf[lane] + x1 * Wf[lane + 64];
    float pi = x0 * Wi[lane] + x1 * Wi[lane + 64];
    float pu = x0 * Wu[lane] + x1 * Wu[lane + 64];
    float po = x0 * Wo[lane] + x1 * Wo[lane + 64];

#pragma unroll
    for (int off = 32; off; off >>= 1) {
        pf += __shfl_xor(pf, off, 64);
        pi += __shfl_xor(pi, off, 64);
        pu += __shfl_xor(pu, off, 64);
        po += __shfl_xor(po, off, 64);
    }
    if (lane == 0) {
        xz[wave] = make_float4(pf + bf[0] + tf[0],
                               pi + bi[0] + ti[0],
                               pu + bu[0] + tu[0],
                               po + bo[0] + to_[0]);
    }
}

// ---------------- Kernel 2: sequential scan, one thread per batch element.
__device__ __forceinline__ float fsig(float x) {
    return __builtin_amdgcn_rcpf(1.0f + __expf(-x));
}
__device__ __forceinline__ float ftanh(float x) {
    float e = __expf(-2.0f * x);
    return (1.0f - e) * __builtin_amdgcn_rcpf(1.0f + e);
}

constexpr int PF = 16;  // prefetch depth (T % PF == 0)

__global__ __launch_bounds__(256) void scan_kernel(
    const float4* __restrict__ xz,
    const float* __restrict__ Wf, const float* __restrict__ Wi,
    const float* __restrict__ Wu, const float* __restrict__ Wo,
    float* __restrict__ hscan, float* __restrict__ cfin)
{
    const int b = threadIdx.x;
    const int wv = threadIdx.x >> 6;
    const int lane = threadIdx.x & 63;

    // wave-parallel sum of W[0][128:] per gate (wave g handles gate g)
    __shared__ float swh[4];
    const float* Wsel = (wv == 0) ? Wf : (wv == 1) ? Wi : (wv == 2) ? Wu : Wo;
    float s = Wsel[128 + lane] + Wsel[192 + lane];
#pragma unroll
    for (int off = 32; off; off >>= 1) s += __shfl_xor(s, off, 64);
    if (lane == 0) swh[wv] = s;
    __syncthreads();
    const float swf = swh[0], swi = swh[1], swu = swh[2], swo = swh[3];

    float h = 0.0f, c = 0.0f;

    // depth-PF rolling register prefetch (all indices static after unroll)
    float4 buf[PF];
#pragma unroll
    for (int d = 0; d < PF; ++d) buf[d] = xz[d * Bsz + b];

    for (int tb = 0; tb < T; tb += PF) {
        const bool more = (tb + PF) < T;
#pragma unroll
        for (int d = 0; d < PF; ++d) {
            const int t = tb + d;
            const float4 z = buf[d];
            if (more) buf[d] = xz[(t + PF) * Bsz + b];

            const float f = fsig(__cosf(z.x + h * swf));
            const float i = fsig(__cosf(z.y + h * swi));
            const float g = ftanh(__cosf(z.z + h * swu));
            const float o = fsig(__cosf(z.w + h * swo));
            c = f * c + i * g;
            h = o * ftanh(c);
            hscan[t * Bsz + b] = h;
        }
    }
    cfin[b] = c;
}

// ---------------- Kernel 3: broadcast h[t,b] across 128 hidden cols, + hx/cx tails.
__global__ __launch_bounds__(256) void bcast_kernel(
    const float* __restrict__ hscan, const float* __restrict__ cfin,
    float4* __restrict__ out)
{
    const unsigned i = blockIdx.x * 256u + threadIdx.x;  // float4 index
    const unsigned row = i >> 5;                          // output row (128 floats)
    float v;
    if (row < (unsigned)R) {
        v = hscan[row];
    } else {
        const unsigned r2 = row - (unsigned)R;
        v = (r2 < (unsigned)Bsz) ? hscan[(T - 1) * Bsz + r2] : cfin[r2 - (unsigned)Bsz];
    }
    out[i] = make_float4(v, v, v, v);
}

extern "C" void kernel_launch(void* const* d_in, const int* in_sizes, int n_in,
                              void* d_out, int out_size, void* d_ws, size_t ws_size,
                              hipStream_t stream)
{
    const float* x  = (const float*)d_in[0];
    const float* Wf = (const float*)d_in[1];
    const float* bf = (const float*)d_in[2];
    const float* tf = (const float*)d_in[3];
    const float* Wi = (const float*)d_in[4];
    const float* bi = (const float*)d_in[5];
    const float* ti = (const float*)d_in[6];
    const float* Wu = (const float*)d_in[7];
    const float* bu = (const float*)d_in[8];
    const float* tu = (const float*)d_in[9];
    const float* Wo = (const float*)d_in[10];
    const float* bo = (const float*)d_in[11];
    const float* to_ = (const float*)d_in[12];

    float* ws    = (float*)d_ws;
    float4* xz   = (float4*)ws;       // R float4s  (4*R floats)
    float* hscan = ws + 4 * R;        // R floats
    float* cfin  = ws + 5 * R;        // Bsz floats

    xz_kernel<<<R / 4, 256, 0, stream>>>(x, Wf, bf, tf, Wi, bi, ti, Wu, bu, tu, Wo, bo, to_, xz);
    scan_kernel<<<1, 256, 0, stream>>>(xz, Wf, Wi, Wu, Wo, hscan, cfin);

    const int total_f4 = (R + 2 * Bsz) * 32;              // 4,210,688
    bcast_kernel<<<total_f4 / 256, 256, 0, stream>>>(hscan, cfin, (float4*)d_out);
}

// Round 3
// 115.493 us; speedup vs baseline: 1.6489x; 1.0947x over previous
//
#include <hip/hip_runtime.h>
#include <hip/hip_bf16.h>

// QLSTM: T=512, B=256, D_IN=128, D_H=128.
// Gates are per-batch SCALARS broadcast over hidden dim => h,c uniform across
// hidden dim. comb@W[0] = x@W[0][:128] + h*sum(W[0][128:]).
// Pipeline: (1) xz GEMV -> packed float4 (REVOLUTIONS: pre-scaled by 1/2pi),
//           (2) 512-step scalar scan, 4 blocks x 1 wave, reg prefetch depth 16,
//               polynomial gates (no exp/rcp-heavy chains),
//           (3) broadcast h[t,b] to 128 cols + hx/cx tails (mem-bound).

constexpr int T = 512;
constexpr int Bsz = 256;
constexpr int D_IN = 128;
constexpr int R = T * Bsz;          // 131072 rows
constexpr float INV2PI = 0.15915494309189535f;

// ---------------- Kernel 1: xz[row] = float4(zf,zi,zu,zo)/(2pi), row = t*B+b
__global__ __launch_bounds__(256) void xz_kernel(
    const float* __restrict__ x,
    const float* __restrict__ Wf, const float* __restrict__ bf, const float* __restrict__ tf,
    const float* __restrict__ Wi, const float* __restrict__ bi, const float* __restrict__ ti,
    const float* __restrict__ Wu, const float* __restrict__ bu, const float* __restrict__ tu,
    const float* __restrict__ Wo, const float* __restrict__ bo, const float* __restrict__ to_,
    float4* __restrict__ xz)
{
    const int wave = blockIdx.x * 4 + (threadIdx.x >> 6);
    const int lane = threadIdx.x & 63;
    const float* xr = x + (size_t)wave * D_IN;
    const float x0 = xr[lane];
    const float x1 = xr[lane + 64];

    float pf = x0 * Wf[lane] + x1 * Wf[lane + 64];
    float pi = x0 * Wi[lane] + x1 * Wi[lane + 64];
    float pu = x0 * Wu[lane] + x1 * Wu[lane + 64];
    float po = x0 * Wo[lane] + x1 * Wo[lane + 64];

#pragma unroll
    for (int off = 32; off; off >>= 1) {
        pf += __shfl_xor(pf, off, 64);
        pi += __shfl_xor(pi, off, 64);
        pu += __shfl_xor(pu, off, 64);
        po += __shfl_xor(po, off, 64);
    }
    if (lane == 0) {
        xz[wave] = make_float4((pf + bf[0] + tf[0]) * INV2PI,
                               (pi + bi[0] + ti[0]) * INV2PI,
                               (pu + bu[0] + tu[0]) * INV2PI,
                               (po + bo[0] + to_[0]) * INV2PI);
    }
}

// ---------------- Kernel 2: sequential scan.
// sigmoid(c), |c|<=1: odd Taylor deg-5 around 0, max err ~2.1e-4 on [-1,1].
__device__ __forceinline__ float sig_poly(float c) {
    const float c2 = c * c;
    float p = fmaf(c2, 1.0f / 480.0f, -1.0f / 48.0f);
    p = fmaf(c2, p, 0.25f);
    return fmaf(c, p, 0.5f);
}
// tanh(u), |u|<=1: Pade[3/2]  u(15+u^2)/(15+6u^2), max err ~3e-4.
__device__ __forceinline__ float tanh_p32(float u) {
    const float u2 = u * u;
    const float num = u2 + 15.0f;
    const float den = fmaf(u2, 6.0f, 15.0f);
    return u * num * __builtin_amdgcn_rcpf(den);
}
// tanh(c), |c|<=~2.1: Pade[5/4]  c(945+105c^2+c^4)/(945+420c^2+15c^4), err ~2e-5.
__device__ __forceinline__ float tanh_p54(float c) {
    const float c2 = c * c;
    const float c4 = c2 * c2;
    const float num = fmaf(c2, 105.0f, 945.0f) + c4;
    const float den = fmaf(c4, 15.0f, fmaf(c2, 420.0f, 945.0f));
    return c * num * __builtin_amdgcn_rcpf(den);
}

__device__ __forceinline__ float wave_wsum(const float* __restrict__ W, int lane) {
    float s = W[128 + lane] + W[192 + lane];
#pragma unroll
    for (int off = 32; off; off >>= 1) s += __shfl_xor(s, off, 64);
    return s;  // butterfly: all lanes hold the sum
}

constexpr int PF = 16;  // prefetch depth (T % PF == 0)

__global__ __launch_bounds__(64, 1) void scan_kernel(
    const float4* __restrict__ xz,
    const float* __restrict__ Wf, const float* __restrict__ Wi,
    const float* __restrict__ Wu, const float* __restrict__ Wo,
    float* __restrict__ hscan, float* __restrict__ cfin)
{
    const int lane = threadIdx.x;
    const int b = blockIdx.x * 64 + lane;

    const float swf = wave_wsum(Wf, lane) * INV2PI;
    const float swi = wave_wsum(Wi, lane) * INV2PI;
    const float swu = wave_wsum(Wu, lane) * INV2PI;
    const float swo = wave_wsum(Wo, lane) * INV2PI;

    float h = 0.0f, c = 0.0f;

    float4 buf[PF];
#pragma unroll
    for (int d = 0; d < PF; ++d) buf[d] = xz[d * Bsz + b];

    for (int tb = 0; tb < T; tb += PF) {
        const bool more = (tb + PF) < T;
#pragma unroll
        for (int d = 0; d < PF; ++d) {
            const int t = tb + d;
            const float4 z = buf[d];
            if (more) buf[d] = xz[(t + PF) * Bsz + b];

            // args already in revolutions
            const float uf = __builtin_amdgcn_cosf(fmaf(h, swf, z.x));
            const float ui = __builtin_amdgcn_cosf(fmaf(h, swi, z.y));
            const float uu = __builtin_amdgcn_cosf(fmaf(h, swu, z.z));
            const float uo = __builtin_amdgcn_cosf(fmaf(h, swo, z.w));

            const float f = sig_poly(uf);
            const float i = sig_poly(ui);
            const float o = sig_poly(uo);
            const float g = tanh_p32(uu);

            c = fmaf(f, c, i * g);
            h = o * tanh_p54(c);
            hscan[t * Bsz + b] = h;
        }
    }
    cfin[b] = c;
}

// ---------------- Kernel 3: broadcast h[t,b] across 128 hidden cols, + hx/cx tails.
__global__ __launch_bounds__(256) void bcast_kernel(
    const float* __restrict__ hscan, const float* __restrict__ cfin,
    float4* __restrict__ out)
{
    const unsigned i = blockIdx.x * 256u + threadIdx.x;  // float4 index
    const unsigned row = i >> 5;                          // output row (128 floats)
    float v;
    if (row < (unsigned)R) {
        v = hscan[row];
    } else {
        const unsigned r2 = row - (unsigned)R;
        v = (r2 < (unsigned)Bsz) ? hscan[(T - 1) * Bsz + r2] : cfin[r2 - (unsigned)Bsz];
    }
    out[i] = make_float4(v, v, v, v);
}

extern "C" void kernel_launch(void* const* d_in, const int* in_sizes, int n_in,
                              void* d_out, int out_size, void* d_ws, size_t ws_size,
                              hipStream_t stream)
{
    const float* x  = (const float*)d_in[0];
    const float* Wf = (const float*)d_in[1];
    const float* bf = (const float*)d_in[2];
    const float* tf = (const float*)d_in[3];
    const float* Wi = (const float*)d_in[4];
    const float* bi = (const float*)d_in[5];
    const float* ti = (const float*)d_in[6];
    const float* Wu = (const float*)d_in[7];
    const float* bu = (const float*)d_in[8];
    const float* tu = (const float*)d_in[9];
    const float* Wo = (const float*)d_in[10];
    const float* bo = (const float*)d_in[11];
    const float* to_ = (const float*)d_in[12];

    float* ws    = (float*)d_ws;
    float4* xz   = (float4*)ws;       // R float4s  (4*R floats)
    float* hscan = ws + 4 * R;        // R floats
    float* cfin  = ws + 5 * R;        // Bsz floats

    xz_kernel<<<R / 4, 256, 0, stream>>>(x, Wf, bf, tf, Wi, bi, ti, Wu, bu, tu, Wo, bo, to_, xz);
    scan_kernel<<<4, 64, 0, stream>>>(xz, Wf, Wi, Wu, Wo, hscan, cfin);

    const int total_f4 = (R + 2 * Bsz) * 32;              // 4,210,688
    bcast_kernel<<<total_f4 / 256, 256, 0, stream>>>(hscan, cfin, (float4*)d_out);
}